// Round 16
// baseline (297.388 us; speedup 1.0000x reference)
//
#include <hip/hip_runtime.h>
#include <hip/hip_bf16.h>
#include <math.h>

typedef short bf16x8 __attribute__((ext_vector_type(8)));
typedef float f32x4 __attribute__((ext_vector_type(4)));
typedef float f32x2 __attribute__((ext_vector_type(2)));
typedef _Float16 f16x2 __attribute__((ext_vector_type(2)));
typedef _Float16 f16x8 __attribute__((ext_vector_type(8)));
typedef __fp16 fp16v2 __attribute__((ext_vector_type(2)));

union ABFrag { int i[4]; bf16x8 v; };
union HFrag { int i[4]; f16x8 v; };

__device__ __forceinline__ float readlane_f(float v, int l) {
    return __uint_as_float(__builtin_amdgcn_readlane(__float_as_uint(v), l));
}

// cold-path pack two f32 -> two bf16 (RNE) in one u32 (lo = a, hi = b)
__device__ __forceinline__ int pack2bf(float a, float b) {
    unsigned ua = __float_as_uint(a);
    unsigned ub = __float_as_uint(b);
    ua = (ua + 0x7FFFu + ((ua >> 16) & 1u)) >> 16;
    ub = (ub + 0x7FFFu + ((ub >> 16) & 1u)) & 0xFFFF0000u;
    return (int)(ua | ub);
}
// hot-path bf16 pack: compiler emits v_cvt_pk_bf16_f32
__device__ __forceinline__ int cvtpk(float a, float b) {
    __hip_bfloat162 h = __float22bfloat162_rn(make_float2(a, b));
    int r; __builtin_memcpy(&r, &h, 4); return r;
}
// fp16 pack: v_cvt_pkrtz_f16_f32
__device__ __forceinline__ int cvtpkh(float a, float b) {
    fp16v2 h = __builtin_amdgcn_cvt_pkrtz(a, b);
    int r; __builtin_memcpy(&r, &h, 4); return r;
}
__device__ __forceinline__ f16x2 cvtpkh2(float a, float b) {
    fp16v2 h = __builtin_amdgcn_cvt_pkrtz(a, b);
    f16x2 r; __builtin_memcpy(&r, &h, 4); return r;
}
__device__ __forceinline__ float bflo(int d) { return __uint_as_float((unsigned)d << 16); }
__device__ __forceinline__ float bfhi(int d) { return __uint_as_float((unsigned)d & 0xFFFF0000u); }

// packed fp16 h-prep: relu(g + a + f*b) on 2 channels, 3 pk ops, no unpack
__device__ __forceinline__ int hp16(int gpk, int apk, int bpk, f16x2 fpk) {
    f16x2 g, a, b;
    __builtin_memcpy(&g, &gpk, 4);
    __builtin_memcpy(&a, &apk, 4);
    __builtin_memcpy(&b, &bpk, 4);
    f16x2 h = g + a + fpk * b;
    f16x2 z = {(_Float16)0.0f, (_Float16)0.0f};
    h = __builtin_elementwise_max(h, z);
    int r; __builtin_memcpy(&r, &h, 4);
    return r;
}

// load pre-packed B-fragment sets
__device__ __forceinline__ void ld8(const int4* __restrict__ P, int lane, ABFrag (&bw)[4][2]) {
#pragma unroll
    for (int nt = 0; nt < 4; ++nt)
#pragma unroll
        for (int kt = 0; kt < 2; ++kt)
            *(int4*)bw[nt][kt].i = P[(nt * 2 + kt) * 64 + lane];
}
__device__ __forceinline__ void ld8h(const int4* __restrict__ P, int lane, HFrag (&bw)[4][2]) {
#pragma unroll
    for (int nt = 0; nt < 4; ++nt)
#pragma unroll
        for (int kt = 0; kt < 2; ++kt)
            *(int4*)bw[nt][kt].i = P[(nt * 2 + kt) * 64 + lane];
}
__device__ __forceinline__ void ld16(const int4* __restrict__ P, int lane, ABFrag (&bw)[4][4]) {
#pragma unroll
    for (int nt = 0; nt < 4; ++nt)
#pragma unroll
        for (int kt = 0; kt < 4; ++kt)
            *(int4*)bw[nt][kt].i = P[(nt * 4 + kt) * 64 + lane];
}

__global__ void zero_int_kernel(int* __restrict__ p, int n) {
    int i = blockIdx.x * blockDim.x + threadIdx.x;
    int stride = gridDim.x * blockDim.x;
    for (; i < n; i += stride) p[i] = 0;
}

// pack all gemm weights into MFMA B-fragment layout (int4 per lane per frag)
// layout (frag-set offsets in int4*64 units):
//   encW2:0  W1a[l]:8+8l  W2[l]:32+8l (fp16!)  U1[l]:56+16l  U2[l]:104+8l  oW1:128
__global__ __launch_bounds__(256)
void wpack_kernel(const float* __restrict__ encW2, const float* __restrict__ mW1,
                  const float* __restrict__ mW2, const float* __restrict__ uW1,
                  const float* __restrict__ uW2, const float* __restrict__ oW1,
                  int4* __restrict__ out) {
    int b = blockIdx.x;
    const float* src; int4* dst; int KT; int F16 = 0;
    if (b == 0)      { src = encW2;                          dst = out;                   KT = 2; }
    else if (b <= 3) { int l = b - 1;  src = mW1 + (size_t)l * 128 * 64; dst = out + (8 + 8 * l) * 64;   KT = 2; }
    else if (b <= 6) { int l = b - 4;  src = mW2 + (size_t)l * 64 * 64;  dst = out + (32 + 8 * l) * 64;  KT = 2; F16 = 1; }
    else if (b <= 9) { int l = b - 7;  src = uW1 + (size_t)l * 128 * 64; dst = out + (56 + 16 * l) * 64; KT = 4; }
    else if (b <= 12){ int l = b - 10; src = uW2 + (size_t)l * 64 * 64;  dst = out + (104 + 8 * l) * 64; KT = 2; }
    else             { src = oW1;                            dst = out + 128 * 64;        KT = 2; }
    int tid = threadIdx.x, lane = tid & 63, w = tid >> 6;
    int n15 = lane & 15, kg = lane >> 4;
    for (int fi = w; fi < 4 * KT; fi += 4) {
        int nt = fi / KT, kt = fi % KT;
        int v[4];
#pragma unroll
        for (int jj = 0; jj < 4; ++jj) {
            int k0 = kt * 32 + kg * 8 + 2 * jj;
            float w0 = src[(size_t)k0 * 64 + nt * 16 + n15];
            float w1 = src[(size_t)(k0 + 1) * 64 + nt * 16 + n15];
            v[jj] = F16 ? cvtpkh(w0, w1) : pack2bf(w0, w1);
        }
        int4 r; r.x = v[0]; r.y = v[1]; r.z = v[2]; r.w = v[3];
        dst[fi * 64 + lane] = r;
    }
}

// XCD-localized histogram: class (blockIdx&7) handles dst range only
__global__ __launch_bounds__(256)
void hist_kernel(const int* __restrict__ EI, int* __restrict__ cnt, int E, int N) {
    int x = blockIdx.x & 7;
    int sl = blockIdx.x >> 3;
    int nsl = gridDim.x >> 3;
    int R = (N + 7) >> 3;
    int lo = x * R;
    int hi = lo + R; if (hi > N) hi = N;
    for (int e = sl * 256 + threadIdx.x; e < E; e += nsl * 256) {
        int dst = EI[E + e];
        if (dst >= lo && dst < hi) atomicAdd(&cnt[dst], 1);
    }
}

// ---- multi-block exclusive scan: cnt[N] -> rowstart[N+1], cursor[N] ----
#define SCAN_B 256

__global__ __launch_bounds__(256)
void scan_part_kernel(const int* __restrict__ cnt, int* __restrict__ bsum, int N) {
    int per = (N + gridDim.x - 1) / gridDim.x;
    int lo = blockIdx.x * per;
    int hi = lo + per; if (hi > N) hi = N;
    int s = 0;
    for (int i = lo + threadIdx.x; i < hi; i += 256) s += cnt[i];
#pragma unroll
    for (int off = 32; off >= 1; off >>= 1) s += __shfl_xor(s, off);
    __shared__ int ws[4];
    if ((threadIdx.x & 63) == 0) ws[threadIdx.x >> 6] = s;
    __syncthreads();
    if (threadIdx.x == 0) bsum[blockIdx.x] = ws[0] + ws[1] + ws[2] + ws[3];
}

__global__ __launch_bounds__(SCAN_B)
void scan_mid_kernel(int* __restrict__ bsum) {
    __shared__ int sbuf[SCAN_B];
    int tid = threadIdx.x;
    int v = bsum[tid];
    sbuf[tid] = v;
    __syncthreads();
#pragma unroll
    for (int d = 1; d < SCAN_B; d <<= 1) {
        int t = (tid >= d) ? sbuf[tid - d] : 0;
        __syncthreads();
        sbuf[tid] += t;
        __syncthreads();
    }
    bsum[tid] = sbuf[tid] - v;   // exclusive
}

__global__ __launch_bounds__(256)
void scan_final_kernel(const int* __restrict__ cnt, const int* __restrict__ bsum,
                       int* __restrict__ rowstart, int* __restrict__ cursor, int N) {
    __shared__ int sbuf[256];
    __shared__ int sbase;
    int per = (N + gridDim.x - 1) / gridDim.x;
    int lo = blockIdx.x * per;
    int hi = lo + per; if (hi > N) hi = N;
    if (threadIdx.x == 0) sbase = bsum[blockIdx.x];
    __syncthreads();
    for (int base = lo; base < hi; base += 256) {
        int i = base + threadIdx.x;
        int v = (i < hi) ? cnt[i] : 0;
        sbuf[threadIdx.x] = v;
        __syncthreads();
#pragma unroll
        for (int d = 1; d < 256; d <<= 1) {
            int t = (threadIdx.x >= d) ? sbuf[threadIdx.x - d] : 0;
            __syncthreads();
            sbuf[threadIdx.x] += t;
            __syncthreads();
        }
        if (i < hi) {
            int ex = sbase + sbuf[threadIdx.x] - v;
            rowstart[i] = ex;
            cursor[i] = ex;
        }
        __syncthreads();
        if (threadIdx.x == 0) sbase += sbuf[255];
        __syncthreads();
    }
    if (blockIdx.x == gridDim.x - 1 && threadIdx.x == 0) rowstart[N] = sbase;
}

// XCD-localized scatter: class (blockIdx&7) writes only its dst range
__global__ __launch_bounds__(256)
void fill_kernel(const int* __restrict__ EI, const float* __restrict__ EF,
                 const float* __restrict__ bp, int* __restrict__ cursor,
                 int2* __restrict__ epack, int E, int N) {
    __shared__ float sbp[64];
    if (threadIdx.x < 64) sbp[threadIdx.x] = bp[threadIdx.x];
    __syncthreads();
    int x = blockIdx.x & 7;
    int sl = blockIdx.x >> 3;
    int nsl = gridDim.x >> 3;
    int R = (N + 7) >> 3;
    int lo = x * R;
    int hi = lo + R; if (hi > N) hi = N;
    for (int e = sl * 256 + threadIdx.x; e < E; e += nsl * 256) {
        int dst = EI[E + e];
        if (dst >= lo && dst < hi) {
            int slot = atomicAdd(&cursor[dst], 1);
            float f = EF[e];
            int sg = 0;
#pragma unroll
            for (int st = 32; st >= 1; st >>= 1)
                if (sg + st <= 64 && sbp[sg + st - 1] < f) sg += st;
            epack[slot] = make_int2(EI[e] | (sg << 25), __float_as_int(f));
        }
    }
}

// sorted breakpoints of f -> relu(f*eW+eB): t_k = -eB_k/eW_k (eW_k != 0)
__global__ __launch_bounds__(64)
void bp_kernel(const float* __restrict__ eW, const float* __restrict__ eB,
               float* __restrict__ bp) {
    int lane = threadIdx.x;
    float w = eW[lane], b = eB[lane];
    float t = (w != 0.f) ? (-b / w) : 1e30f;
    __shared__ float sbp[64];
    int rank = 0;
    for (int j = 0; j < 64; ++j) {
        float tj = readlane_f(t, j);
        rank += (tj < t) || (tj == t && j < lane);
    }
    sbp[rank] = t;
    __syncthreads();
    bp[lane] = sbp[lane];
}

// per (layer, segment): A[j],B[j] summed over active units; stored as packed
// fp16 PAIRS in two planes (A at dwords 0..31, B at 32..63 per segment),
// chunk-XOR-swizzled so msg staging is a raw copy.
__global__ __launch_bounds__(64)
void tab_kernel(const float* __restrict__ eW, const float* __restrict__ eB,
                const float* __restrict__ mW1, const float* __restrict__ bp,
                int* __restrict__ Tpk) {
    int s = blockIdx.x % 65;
    int l = blockIdx.x / 65;
    int j = threadIdx.x;
    float lo = (s == 0) ? 0.f : bp[s - 1];
    float hi = (s == 64) ? 0.f : bp[s];
    float rep;
    if (s == 0) rep = hi - fmaxf(1.f, fabsf(hi));
    else if (s == 64) rep = lo + fmaxf(1.f, fabsf(lo));
    else rep = 0.5f * (lo + hi);
    const float* W1b = mW1 + (size_t)l * 128 * 64 + 64 * 64;
    float A = 0.f, B = 0.f;
    for (int k = 0; k < 64; ++k) {
        float w = eW[k], b = eB[k];
        if (fmaf(rep, w, b) > 0.f) {
            float wv = W1b[k * 64 + j];
            A = fmaf(b, wv, A);
            B = fmaf(w, wv, B);
        }
    }
    float Ao = __shfl_xor(A, 1), Bo = __shfl_xor(B, 1);
    if ((j & 1) == 0) {
        int p = j >> 1;            // pair index 0..31
        int c = p >> 2;            // chunk 0..7
        int base = (s << 6) + (((c ^ (s & 7)) << 2) | (p & 3));
        int* dst = Tpk + (size_t)l * 65 * 64;
        dst[base] = cvtpkh(A, Ao);
        dst[base + 32] = cvtpkh(B, Bo);
    }
}

// first encoder layer, bf16 out: Y[n,j] = relu(b[j] + sum_{k<5} NF[n,k]*W[k,j])
__global__ __launch_bounds__(256)
void enc1_kernel(const float* __restrict__ NF, const float* __restrict__ W,
                 const float* __restrict__ b, unsigned short* __restrict__ Y, int N) {
    int lane = threadIdx.x & 63;
    float w0 = W[0 * 64 + lane], w1 = W[1 * 64 + lane], w2 = W[2 * 64 + lane];
    float w3 = W[3 * 64 + lane], w4 = W[4 * 64 + lane];
    float bv = b[lane];
    int wid = (blockIdx.x * blockDim.x + threadIdx.x) >> 6;
    int nw = (gridDim.x * blockDim.x) >> 6;
    for (int n = wid; n < N; n += nw) {
        float x = (lane < 5) ? NF[n * 5 + lane] : 0.f;
        float acc = bv;
        acc = fmaf(readlane_f(x, 0), w0, acc);
        acc = fmaf(readlane_f(x, 1), w1, acc);
        acc = fmaf(readlane_f(x, 2), w2, acc);
        acc = fmaf(readlane_f(x, 3), w3, acc);
        acc = fmaf(readlane_f(x, 4), w4, acc);
        acc = fmaxf(acc, 0.f);
        float o = __shfl_xor(acc, 1);
        if ((lane & 1) == 0) *(int*)(Y + (size_t)n * 64 + lane) = cvtpk(acc, o);
    }
}

// MFMA node-gemm (bf16 in/out) with optional fused second gemm (Gout fp16 = Y@Wg + bg)
template <int RELU, int FUSE>
__global__ __launch_bounds__(256, 2)
void ngemm_kernel(const unsigned short* __restrict__ X, const int4* __restrict__ pW,
                  const float* __restrict__ b, unsigned short* __restrict__ Y,
                  const int4* __restrict__ pWg, const float* __restrict__ bg,
                  unsigned short* __restrict__ Gout, int N) {
    __shared__ unsigned short sT[4][16 * 72];
    int tid = threadIdx.x;
    int lane = tid & 63, w = tid >> 6;
    int n15 = lane & 15, kg = lane >> 4;
    unsigned short* T = sT[w];
    ABFrag bw[4][2], bwg[4][2];
    ld8(pW, lane, bw);
    if (FUSE) ld8(pWg, lane, bwg);
    float bv[4], bgv[4];
#pragma unroll
    for (int nt = 0; nt < 4; ++nt) {
        bv[nt] = b[nt * 16 + n15];
        bgv[nt] = FUSE ? bg[nt * 16 + n15] : 0.f;
    }

    int wid = (blockIdx.x * blockDim.x + tid) >> 6;
    int nw = (gridDim.x * blockDim.x) >> 6;
    int nTiles = (N + 15) >> 4;
    bool ev = ((n15 & 1) == 0);
    for (int t = wid; t < nTiles; t += nw) {
        int n0 = t << 4;
        int row = n0 + n15; if (row > N - 1) row = N - 1;
        ABFrag A0, A1;
        const unsigned short* xp = X + (size_t)row * 64 + kg * 8;
        *(int4*)A0.i = *(const int4*)xp;
        *(int4*)A1.i = *(const int4*)(xp + 32);
        f32x4 acc[4];
#pragma unroll
        for (int nt = 0; nt < 4; ++nt) {
            acc[nt][0] = bv[nt]; acc[nt][1] = bv[nt];
            acc[nt][2] = bv[nt]; acc[nt][3] = bv[nt];
        }
#pragma unroll
        for (int nt = 0; nt < 4; ++nt) {
            acc[nt] = __builtin_amdgcn_mfma_f32_16x16x32_bf16(A0.v, bw[nt][0].v, acc[nt], 0, 0, 0);
            acc[nt] = __builtin_amdgcn_mfma_f32_16x16x32_bf16(A1.v, bw[nt][1].v, acc[nt], 0, 0, 0);
        }
        if (FUSE) {
            asm volatile("s_waitcnt lgkmcnt(0)" ::: "memory");
            __builtin_amdgcn_sched_barrier(0);
        }
#pragma unroll
        for (int nt = 0; nt < 4; ++nt) {
            float v0 = acc[nt][0], v1 = acc[nt][1], v2 = acc[nt][2], v3 = acc[nt][3];
            if (RELU) {
                v0 = fmaxf(v0, 0.f); v1 = fmaxf(v1, 0.f);
                v2 = fmaxf(v2, 0.f); v3 = fmaxf(v3, 0.f);
            }
            float o0 = __shfl_xor(v0, 1), o1 = __shfl_xor(v1, 1);
            float o2 = __shfl_xor(v2, 1), o3 = __shfl_xor(v3, 1);
            int colb = nt * 16 + (n15 & ~1);
            int p0 = cvtpk(v0, o0), p1 = cvtpk(v1, o1);
            int p2 = cvtpk(o2, v2), p3 = cvtpk(o3, v3);
            if (ev) {
                int r0 = n0 + kg * 4 + 0, r1 = n0 + kg * 4 + 1;
                if (r0 < N) *(int*)(Y + (size_t)r0 * 64 + colb) = p0;
                if (r1 < N) *(int*)(Y + (size_t)r1 * 64 + colb) = p1;
                if (FUSE) {
                    *(int*)(T + (kg * 4 + 0) * 72 + colb) = p0;
                    *(int*)(T + (kg * 4 + 1) * 72 + colb) = p1;
                }
            } else {
                int r2 = n0 + kg * 4 + 2, r3 = n0 + kg * 4 + 3;
                if (r2 < N) *(int*)(Y + (size_t)r2 * 64 + colb) = p2;
                if (r3 < N) *(int*)(Y + (size_t)r3 * 64 + colb) = p3;
                if (FUSE) {
                    *(int*)(T + (kg * 4 + 2) * 72 + colb) = p2;
                    *(int*)(T + (kg * 4 + 3) * 72 + colb) = p3;
                }
            }
        }
        if (FUSE) {
            asm volatile("s_waitcnt lgkmcnt(0)" ::: "memory");
            __builtin_amdgcn_sched_barrier(0);
            ABFrag T0, T1;
            *(int4*)T0.i = *(const int4*)(T + n15 * 72 + kg * 8);
            *(int4*)T1.i = *(const int4*)(T + n15 * 72 + 32 + kg * 8);
            f32x4 g[4];
#pragma unroll
            for (int nt = 0; nt < 4; ++nt) {
                g[nt][0] = bgv[nt]; g[nt][1] = bgv[nt];
                g[nt][2] = bgv[nt]; g[nt][3] = bgv[nt];
            }
#pragma unroll
            for (int nt = 0; nt < 4; ++nt) {
                g[nt] = __builtin_amdgcn_mfma_f32_16x16x32_bf16(T0.v, bwg[nt][0].v, g[nt], 0, 0, 0);
                g[nt] = __builtin_amdgcn_mfma_f32_16x16x32_bf16(T1.v, bwg[nt][1].v, g[nt], 0, 0, 0);
            }
#pragma unroll
            for (int nt = 0; nt < 4; ++nt) {
                float v0 = g[nt][0], v1 = g[nt][1], v2 = g[nt][2], v3 = g[nt][3];
                float o0 = __shfl_xor(v0, 1), o1 = __shfl_xor(v1, 1);
                float o2 = __shfl_xor(v2, 1), o3 = __shfl_xor(v3, 1);
                int colb = nt * 16 + (n15 & ~1);
                if (ev) {
                    int r0 = n0 + kg * 4 + 0, r1 = n0 + kg * 4 + 1;
                    if (r0 < N) *(int*)(Gout + (size_t)r0 * 64 + colb) = cvtpkh(v0, o0);
                    if (r1 < N) *(int*)(Gout + (size_t)r1 * 64 + colb) = cvtpkh(v1, o1);
                } else {
                    int r2 = n0 + kg * 4 + 2, r3 = n0 + kg * 4 + 3;
                    if (r2 < N) *(int*)(Gout + (size_t)r2 * 64 + colb) = cvtpkh(o2, v2);
                    if (r3 < N) *(int*)(Gout + (size_t)r3 * 64 + colb) = cvtpkh(o3, v3);
                }
            }
        }
    }
}

// fused update MLP (+optional next-layer gbf fp16): bf16 activations, packed weights
template <int FUSE>
__global__ __launch_bounds__(256, 2)
void upd_kernel(const unsigned short* __restrict__ X1, const unsigned short* __restrict__ X2,
                const int4* __restrict__ pU1, const float* __restrict__ v1,
                const int4* __restrict__ pU2, const float* __restrict__ v2,
                unsigned short* __restrict__ Y,
                const int4* __restrict__ pWg, const float* __restrict__ bg,
                unsigned short* __restrict__ Gout, int N) {
    __shared__ unsigned short sT[4][16 * 72];
    int tid = threadIdx.x, lane = tid & 63, w = tid >> 6;
    int n15 = lane & 15, kg = lane >> 4;
    unsigned short* T = sT[w];

    ABFrag bw1[4][4], bw2[4][2], bwg[4][2];
    ld16(pU1, lane, bw1);
    ld8(pU2, lane, bw2);
    if (FUSE) ld8(pWg, lane, bwg);
    float b1v[4], b2v[4], bgv[4];
#pragma unroll
    for (int nt = 0; nt < 4; ++nt) {
        b1v[nt] = v1[nt * 16 + n15];
        b2v[nt] = v2[nt * 16 + n15];
        bgv[nt] = FUSE ? bg[nt * 16 + n15] : 0.f;
    }

    int wid = (blockIdx.x * blockDim.x + tid) >> 6;
    int nw = (gridDim.x * blockDim.x) >> 6;
    int nTiles = (N + 15) >> 4;
    bool ev = ((n15 & 1) == 0);
    for (int t = wid; t < nTiles; t += nw) {
        int n0 = t << 4;
        int row = n0 + n15; if (row > N - 1) row = N - 1;
        ABFrag A0, A1, A2, A3;
        const unsigned short* xp = X1 + (size_t)row * 64 + kg * 8;
        *(int4*)A0.i = *(const int4*)xp;
        *(int4*)A1.i = *(const int4*)(xp + 32);
        const unsigned short* yp = X2 + (size_t)row * 64 + kg * 8;
        *(int4*)A2.i = *(const int4*)yp;
        *(int4*)A3.i = *(const int4*)(yp + 32);
        f32x4 a1[4];
#pragma unroll
        for (int nt = 0; nt < 4; ++nt) {
            a1[nt][0] = b1v[nt]; a1[nt][1] = b1v[nt];
            a1[nt][2] = b1v[nt]; a1[nt][3] = b1v[nt];
        }
#pragma unroll
        for (int nt = 0; nt < 4; ++nt) {
            a1[nt] = __builtin_amdgcn_mfma_f32_16x16x32_bf16(A0.v, bw1[nt][0].v, a1[nt], 0, 0, 0);
            a1[nt] = __builtin_amdgcn_mfma_f32_16x16x32_bf16(A1.v, bw1[nt][1].v, a1[nt], 0, 0, 0);
            a1[nt] = __builtin_amdgcn_mfma_f32_16x16x32_bf16(A2.v, bw1[nt][2].v, a1[nt], 0, 0, 0);
            a1[nt] = __builtin_amdgcn_mfma_f32_16x16x32_bf16(A3.v, bw1[nt][3].v, a1[nt], 0, 0, 0);
        }
        // t1 (relu, bf16) -> per-wave LDS tile, stride 72
        asm volatile("s_waitcnt lgkmcnt(0)" ::: "memory");
        __builtin_amdgcn_sched_barrier(0);
#pragma unroll
        for (int nt = 0; nt < 4; ++nt) {
            float v0 = fmaxf(a1[nt][0], 0.f), v1_ = fmaxf(a1[nt][1], 0.f);
            float v2_ = fmaxf(a1[nt][2], 0.f), v3 = fmaxf(a1[nt][3], 0.f);
            float o0 = __shfl_xor(v0, 1), o1 = __shfl_xor(v1_, 1);
            float o2 = __shfl_xor(v2_, 1), o3 = __shfl_xor(v3, 1);
            int colb = nt * 16 + (n15 & ~1);
            if (ev) {
                *(int*)(T + (kg * 4 + 0) * 72 + colb) = cvtpk(v0, o0);
                *(int*)(T + (kg * 4 + 1) * 72 + colb) = cvtpk(v1_, o1);
            } else {
                *(int*)(T + (kg * 4 + 2) * 72 + colb) = cvtpk(o2, v2_);
                *(int*)(T + (kg * 4 + 3) * 72 + colb) = cvtpk(o3, v3);
            }
        }
        asm volatile("s_waitcnt lgkmcnt(0)" ::: "memory");
        __builtin_amdgcn_sched_barrier(0);
        ABFrag T0, T1;
        *(int4*)T0.i = *(const int4*)(T + n15 * 72 + kg * 8);
        *(int4*)T1.i = *(const int4*)(T + n15 * 72 + 32 + kg * 8);
        f32x4 a2[4];
#pragma unroll
        for (int nt = 0; nt < 4; ++nt) {
            a2[nt][0] = b2v[nt]; a2[nt][1] = b2v[nt];
            a2[nt][2] = b2v[nt]; a2[nt][3] = b2v[nt];
        }
#pragma unroll
        for (int nt = 0; nt < 4; ++nt) {
            a2[nt] = __builtin_amdgcn_mfma_f32_16x16x32_bf16(T0.v, bw2[nt][0].v, a2[nt], 0, 0, 0);
            a2[nt] = __builtin_amdgcn_mfma_f32_16x16x32_bf16(T1.v, bw2[nt][1].v, a2[nt], 0, 0, 0);
        }
        asm volatile("s_waitcnt lgkmcnt(0)" ::: "memory");
        __builtin_amdgcn_sched_barrier(0);
#pragma unroll
        for (int nt = 0; nt < 4; ++nt) {
            float v0 = fmaxf(a2[nt][0], 0.f), v1_ = fmaxf(a2[nt][1], 0.f);
            float v2_ = fmaxf(a2[nt][2], 0.f), v3 = fmaxf(a2[nt][3], 0.f);
            float o0 = __shfl_xor(v0, 1), o1 = __shfl_xor(v1_, 1);
            float o2 = __shfl_xor(v2_, 1), o3 = __shfl_xor(v3, 1);
            int colb = nt * 16 + (n15 & ~1);
            int p0 = cvtpk(v0, o0), p1 = cvtpk(v1_, o1);
            int p2 = cvtpk(o2, v2_), p3 = cvtpk(o3, v3);
            if (ev) {
                int r0 = n0 + kg * 4 + 0, r1 = n0 + kg * 4 + 1;
                if (r0 < N) *(int*)(Y + (size_t)r0 * 64 + colb) = p0;
                if (r1 < N) *(int*)(Y + (size_t)r1 * 64 + colb) = p1;
                if (FUSE) {
                    *(int*)(T + (kg * 4 + 0) * 72 + colb) = p0;
                    *(int*)(T + (kg * 4 + 1) * 72 + colb) = p1;
                }
            } else {
                int r2 = n0 + kg * 4 + 2, r3 = n0 + kg * 4 + 3;
                if (r2 < N) *(int*)(Y + (size_t)r2 * 64 + colb) = p2;
                if (r3 < N) *(int*)(Y + (size_t)r3 * 64 + colb) = p3;
                if (FUSE) {
                    *(int*)(T + (kg * 4 + 2) * 72 + colb) = p2;
                    *(int*)(T + (kg * 4 + 3) * 72 + colb) = p3;
                }
            }
        }
        if (FUSE) {
            asm volatile("s_waitcnt lgkmcnt(0)" ::: "memory");
            __builtin_amdgcn_sched_barrier(0);
            ABFrag G0, G1;
            *(int4*)G0.i = *(const int4*)(T + n15 * 72 + kg * 8);
            *(int4*)G1.i = *(const int4*)(T + n15 * 72 + 32 + kg * 8);
            f32x4 g[4];
#pragma unroll
            for (int nt = 0; nt < 4; ++nt) {
                g[nt][0] = bgv[nt]; g[nt][1] = bgv[nt];
                g[nt][2] = bgv[nt]; g[nt][3] = bgv[nt];
            }
#pragma unroll
            for (int nt = 0; nt < 4; ++nt) {
                g[nt] = __builtin_amdgcn_mfma_f32_16x16x32_bf16(G0.v, bwg[nt][0].v, g[nt], 0, 0, 0);
                g[nt] = __builtin_amdgcn_mfma_f32_16x16x32_bf16(G1.v, bwg[nt][1].v, g[nt], 0, 0, 0);
            }
#pragma unroll
            for (int nt = 0; nt < 4; ++nt) {
                float v0 = g[nt][0], v1_ = g[nt][1], v2_ = g[nt][2], v3 = g[nt][3];
                float o0 = __shfl_xor(v0, 1), o1 = __shfl_xor(v1_, 1);
                float o2 = __shfl_xor(v2_, 1), o3 = __shfl_xor(v3, 1);
                int colb = nt * 16 + (n15 & ~1);
                if (ev) {
                    int r0 = n0 + kg * 4 + 0, r1 = n0 + kg * 4 + 1;
                    if (r0 < N) *(int*)(Gout + (size_t)r0 * 64 + colb) = cvtpkh(v0, o0);
                    if (r1 < N) *(int*)(Gout + (size_t)r1 * 64 + colb) = cvtpkh(v1_, o1);
                } else {
                    int r2 = n0 + kg * 4 + 2, r3 = n0 + kg * 4 + 3;
                    if (r2 < N) *(int*)(Gout + (size_t)r2 * 64 + colb) = cvtpkh(o2, v2_);
                    if (r3 < N) *(int*)(Gout + (size_t)r3 * 64 + colb) = cvtpkh(o3, v3);
                }
            }
        }
    }
}

// node-per-wave fp16 MFMA message kernel (no atomics), XCD-local strided nodes,
// 2-stage software pipeline: Gbf load for tile t+1 issued during tile t compute.
__global__ __launch_bounds__(256, 4)
void msg_mfma_kernel(const unsigned short* __restrict__ Gh, const int* __restrict__ rowstart,
                     const int2* __restrict__ epack, const int* __restrict__ Tpk,
                     const int4* __restrict__ pW2, const float* __restrict__ b2p,
                     unsigned short* __restrict__ AggBf, int N) {
    __shared__ int sT[65 * 64];
    int tid = threadIdx.x;
    for (int i = tid; i < 65 * 64; i += 256) sT[i] = Tpk[i];
    int lane = tid & 63;
    int n15 = lane & 15;
    int kg = lane >> 4;

    HFrag bw[4][2];
    ld8h(pW2, lane, bw);
    float b2v[4], pb2[4];
#pragma unroll
    for (int nt = 0; nt < 4; ++nt) { b2v[nt] = b2p[nt * 16 + n15]; pb2[nt] = fmaxf(b2v[nt], 0.f); }
    __syncthreads();

    // XCD-local node range (matches fill's dst partition), strided across waves
    int x = blockIdx.x & 7;
    int R = (N + 7) >> 3;
    int lo = x * R;
    int hi = lo + R; if (hi > N) hi = N;
    int wic = ((blockIdx.x >> 3) << 2) + (tid >> 6);
    int nwc = (gridDim.x >> 3) << 2;

    const f32x4 z4 = {0.f, 0.f, 0.f, 0.f};
    for (int n = lo + wic; n < hi; n += nwc) {
        int beg = rowstart[n], end = rowstart[n + 1];
        int d = end - beg;
        float na[4] = {0.f, 0.f, 0.f, 0.f};
        if (d > 0) {
            // pipeline prologue: ep+g for tile0; ep for tile1
            int e0 = beg + n15;
            int2 epCur = epack[(e0 < end) ? e0 : beg];
            int srcC = epCur.x & 0x1FFFFFF;
            const unsigned short* gpC = Gh + (size_t)srcC * 64 + kg * 8;
            int4 gaC = *(const int4*)gpC;
            int4 gbC = *(const int4*)(gpC + 32);
            int2 epNxt = epCur;
            if (beg + 16 < end) {
                int e1 = beg + 16 + n15;
                epNxt = epack[(e1 < end) ? e1 : beg];
            }
            for (int t0 = beg; t0 < end; t0 += 16) {
                int2 ep = epCur;
                int4 ga = gaC, gb = gbC;
                int t1 = t0 + 16;
                if (t1 < end) {
                    // issue next tile's Gbf load NOW (overlaps this tile's compute)
                    int srcN = epNxt.x & 0x1FFFFFF;
                    const unsigned short* gpN = Gh + (size_t)srcN * 64 + kg * 8;
                    gaC = *(const int4*)gpN;
                    gbC = *(const int4*)(gpN + 32);
                    epCur = epNxt;
                    int t2 = t1 + 16;
                    if (t2 < end) {
                        int e2 = t2 + n15;
                        epNxt = epack[(e2 < end) ? e2 : beg];
                    }
                }
                int sg = (int)(((unsigned)ep.x) >> 25);
                f16x2 fpk = cvtpkh2(__int_as_float(ep.y), __int_as_float(ep.y));
                int sgb = sg << 6, sx = sg & 7;
                int4 tA0 = *(const int4*)&sT[sgb + (((kg ^ sx)) << 2)];
                int4 tA1 = *(const int4*)&sT[sgb + ((((4 + kg) ^ sx)) << 2)];
                int4 tB0 = *(const int4*)&sT[sgb + 32 + (((kg ^ sx)) << 2)];
                int4 tB1 = *(const int4*)&sT[sgb + 32 + ((((4 + kg) ^ sx)) << 2)];
                HFrag A0, A1;
                A0.i[0] = hp16(ga.x, tA0.x, tB0.x, fpk);
                A0.i[1] = hp16(ga.y, tA0.y, tB0.y, fpk);
                A0.i[2] = hp16(ga.z, tA0.z, tB0.z, fpk);
                A0.i[3] = hp16(ga.w, tA0.w, tB0.w, fpk);
                A1.i[0] = hp16(gb.x, tA1.x, tB1.x, fpk);
                A1.i[1] = hp16(gb.y, tA1.y, tB1.y, fpk);
                A1.i[2] = hp16(gb.z, tA1.z, tB1.z, fpk);
                A1.i[3] = hp16(gb.w, tA1.w, tB1.w, fpk);
                int rem = end - t0;
                if (rem < 16) {
                    // zero pad rows (lanes); they contribute exactly relu(b2) per
                    // col, removed by the per-node correction below
                    int zm = (n15 < rem) ? -1 : 0;
#pragma unroll
                    for (int j = 0; j < 4; ++j) { A0.i[j] &= zm; A1.i[j] &= zm; }
                }
                f32x4 acc[4];
#pragma unroll
                for (int nt = 0; nt < 4; ++nt) {
                    acc[nt][0] = b2v[nt]; acc[nt][1] = b2v[nt];
                    acc[nt][2] = b2v[nt]; acc[nt][3] = b2v[nt];
                }
#pragma unroll
                for (int nt = 0; nt < 4; ++nt) {
                    acc[nt] = __builtin_amdgcn_mfma_f32_16x16x32_f16(A0.v, bw[nt][0].v, acc[nt], 0, 0, 0);
                    acc[nt] = __builtin_amdgcn_mfma_f32_16x16x32_f16(A1.v, bw[nt][1].v, acc[nt], 0, 0, 0);
                }
#pragma unroll
                for (int nt = 0; nt < 4; ++nt) {
                    f32x4 m = __builtin_elementwise_max(acc[nt], z4);
                    na[nt] += (m[0] + m[1]) + (m[2] + m[3]);
                }
            }
        }
        // cross-lane kg reduction, once per node
#pragma unroll
        for (int nt = 0; nt < 4; ++nt) {
            float v = na[nt];
            v += __shfl_xor(v, 16);
            v += __shfl_xor(v, 32);
            na[nt] = v;
        }
        // remove pad-row contributions, mean, select col = lane, store bf16
        int tiles = (d + 15) >> 4;
        float pad = (float)((tiles << 4) - d);
        float invd = (d > 0) ? (1.f / (float)d) : 1.f;
        float s0 = fmaf(-pad, pb2[0], na[0]);
        float s1 = fmaf(-pad, pb2[1], na[1]);
        float s2 = fmaf(-pad, pb2[2], na[2]);
        float s3 = fmaf(-pad, pb2[3], na[3]);
        float sel = s0;
        sel = (kg == 1) ? s1 : sel;
        sel = (kg == 2) ? s2 : sel;
        sel = (kg == 3) ? s3 : sel;
        sel *= invd;
        float o = __shfl_xor(sel, 1);
        if ((lane & 1) == 0) *(int*)(AggBf + (size_t)n * 64 + lane) = cvtpk(sel, o);
    }
}

// fused head: t = relu(X1@W1+b1); pred = t@W2+b2; out = 2pi*sigmoid(pred); X1 bf16
__global__ __launch_bounds__(256, 2)
void headf_kernel(const unsigned short* __restrict__ X1, const int4* __restrict__ pW1,
                  const float* __restrict__ b1, const float* __restrict__ W2,
                  const float* __restrict__ b2, float* __restrict__ out, int N) {
    int tid = threadIdx.x, lane = tid & 63;
    int n15 = lane & 15, kg = lane >> 4;
    ABFrag bw[4][2];
    ld8(pW1, lane, bw);
    float bv[4];
#pragma unroll
    for (int nt = 0; nt < 4; ++nt) bv[nt] = b1[nt * 16 + n15];
    float w2r[3][4];
#pragma unroll
    for (int nt = 0; nt < 4; ++nt) {
        int col = nt * 16 + n15;
        w2r[0][nt] = W2[col * 3 + 0];
        w2r[1][nt] = W2[col * 3 + 1];
        w2r[2][nt] = W2[col * 3 + 2];
    }
    float b20 = b2[0], b21 = b2[1], b22 = b2[2];
    const float TWO_PI = 6.283185307179586f;

    int wid = (blockIdx.x * blockDim.x + tid) >> 6;
    int nw = (gridDim.x * blockDim.x) >> 6;
    int nTiles = (N + 15) >> 4;
    for (int t = wid; t < nTiles; t += nw) {
        int n0 = t << 4;
        int row = n0 + n15; if (row > N - 1) row = N - 1;
        ABFrag A0, A1;
        const unsigned short* xp = X1 + (size_t)row * 64 + kg * 8;
        *(int4*)A0.i = *(const int4*)xp;
        *(int4*)A1.i = *(const int4*)(xp + 32);
        f32x4 acc[4];
#pragma unroll
        for (int nt = 0; nt < 4; ++nt) {
            acc[nt][0] = bv[nt]; acc[nt][1] = bv[nt];
            acc[nt][2] = bv[nt]; acc[nt][3] = bv[nt];
        }
#pragma unroll
        for (int nt = 0; nt < 4; ++nt) {
            acc[nt] = __builtin_amdgcn_mfma_f32_16x16x32_bf16(A0.v, bw[nt][0].v, acc[nt], 0, 0, 0);
            acc[nt] = __builtin_amdgcn_mfma_f32_16x16x32_bf16(A1.v, bw[nt][1].v, acc[nt], 0, 0, 0);
        }
#pragma unroll
        for (int r = 0; r < 4; ++r) {
            float p0 = 0.f, p1 = 0.f, p2 = 0.f;
#pragma unroll
            for (int nt = 0; nt < 4; ++nt) {
                float tv = fmaxf(acc[nt][r], 0.f);
                p0 = fmaf(tv, w2r[0][nt], p0);
                p1 = fmaf(tv, w2r[1][nt], p1);
                p2 = fmaf(tv, w2r[2][nt], p2);
            }
#pragma unroll
            for (int off = 1; off <= 8; off <<= 1) {
                p0 += __shfl_xor(p0, off);
                p1 += __shfl_xor(p1, off);
                p2 += __shfl_xor(p2, off);
            }
            int rr = n0 + kg * 4 + r;
            if (n15 == 0 && rr < N) {
                float v0 = p0 + b20, v1 = p1 + b21, v2 = p2 + b22;
                out[rr * 3 + 0] = TWO_PI / (1.f + expf(-v0));
                out[rr * 3 + 1] = TWO_PI / (1.f + expf(-v1));
                out[rr * 3 + 2] = TWO_PI / (1.f + expf(-v2));
            }
        }
    }
}

extern "C" void kernel_launch(void* const* d_in, const int* in_sizes, int n_in,
                              void* d_out, int out_size, void* d_ws, size_t ws_size,
                              hipStream_t stream) {
    const float* nf    = (const float*)d_in[0];
    const int*   ei    = (const int*)d_in[1];
    const float* ef    = (const float*)d_in[2];
    const float* encW1 = (const float*)d_in[3];
    const float* encb1 = (const float*)d_in[4];
    const float* encW2 = (const float*)d_in[5];
    const float* encb2 = (const float*)d_in[6];
    const float* eeW   = (const float*)d_in[7];
    const float* eeb   = (const float*)d_in[8];
    const float* mW1   = (const float*)d_in[9];
    const float* mb1   = (const float*)d_in[10];
    const float* mW2   = (const float*)d_in[11];
    const float* mb2   = (const float*)d_in[12];
    const float* uW1   = (const float*)d_in[13];
    const float* ub1   = (const float*)d_in[14];
    const float* uW2   = (const float*)d_in[15];
    const float* ub2   = (const float*)d_in[16];
    const float* oW1   = (const float*)d_in[17];
    const float* ob1   = (const float*)d_in[18];
    const float* oW2   = (const float*)d_in[19];
    const float* ob2   = (const float*)d_in[20];
    float* out = (float*)d_out;

    int N = in_sizes[0] / 5;   // 50000
    int E = in_sizes[2];       // 800000
    size_t N64 = (size_t)N * 64;

    unsigned short* hA    = (unsigned short*)d_ws;       // N64 bf16
    unsigned short* hB    = hA + N64;                    // N64 bf16
    unsigned short* gbf   = hB + N64;                    // N64 fp16 (also enc tmp bf16)
    unsigned short* aggbf = gbf + N64;                   // N64 bf16
    int2* epack = (int2*)(aggbf + N64);                  // E int2
    float* bp   = (float*)(epack + E);                   // 64
    int* Tpk    = (int*)(bp + 64);                       // 3*65*64
    int4* pw    = (int4*)(Tpk + 3 * 65 * 64);            // 136*64 int4 (packed weights)
    int* rowstart = (int*)(pw + 136 * 64);               // N+8
    int* cursor   = rowstart + N + 8;                    // N
    int* dcnt     = cursor + N;                          // N
    int* bsum     = dcnt + N;                            // SCAN_B

    const int4* pEncW2 = pw;
    const int4* pW1a0  = pw + (size_t)8 * 64;
    const int4* pOW1   = pw + (size_t)128 * 64;

    int gemmBlocks = ((N + 15) / 16 + 7) / 8;            // 2 tiles per wave

    // packed weights + piecewise-linear tables (fixed inputs)
    wpack_kernel<<<14, 256, 0, stream>>>(encW2, mW1, mW2, uW1, uW2, oW1, pw);
    bp_kernel<<<1, 64, 0, stream>>>(eeW, eeb, bp);
    tab_kernel<<<195, 64, 0, stream>>>(eeW, eeb, mW1, bp, Tpk);

    // node encoder (+fused fp16 gbf for layer 0)
    enc1_kernel<<<512, 256, 0, stream>>>(nf, encW1, encb1, gbf, N);
    ngemm_kernel<1, 1><<<gemmBlocks, 256, 0, stream>>>(gbf, pEncW2, encb2, hA,
                                                       pW1a0, mb1, gbf, N);

    // CSR build (dst-sorted edge list), XCD-localized hist/scatter
    zero_int_kernel<<<256, 256, 0, stream>>>(dcnt, N);
    hist_kernel<<<2048, 256, 0, stream>>>(ei, dcnt, E, N);
    scan_part_kernel<<<SCAN_B, 256, 0, stream>>>(dcnt, bsum, N);
    scan_mid_kernel<<<1, SCAN_B, 0, stream>>>(bsum);
    scan_final_kernel<<<SCAN_B, 256, 0, stream>>>(dcnt, bsum, rowstart, cursor, N);
    fill_kernel<<<2048, 256, 0, stream>>>(ei, ef, bp, cursor, epack, E, N);

    unsigned short* h  = hA;
    unsigned short* hn = hB;
    for (int l = 0; l < 3; ++l) {
        const int4* pW2 = pw + (size_t)(32 + 8 * l) * 64;
        const float* b2 = mb2 + l * 64;
        // aggbf = mean over in-edges of relu(relu(G+ce)@W2+b2)   (fp16 datapath)
        msg_mfma_kernel<<<2048, 256, 0, stream>>>(gbf, rowstart, epack,
                                                  Tpk + (size_t)l * 65 * 64,
                                                  pW2, b2, aggbf, N);
        const int4* pU1 = pw + (size_t)(56 + 16 * l) * 64;
        const int4* pU2 = pw + (size_t)(104 + 8 * l) * 64;
        const float* v1 = ub1 + l * 64;
        const float* v2 = ub2 + l * 64;
        // hn = relu(relu([h|aggbf]@U1+v1)@U2+v2)  (+fused next-layer fp16 gbf)
        if (l < 2) {
            const int4* pW1n = pw + (size_t)(8 + 8 * (l + 1)) * 64;
            const float* b1n = mb1 + (l + 1) * 64;
            upd_kernel<1><<<gemmBlocks, 256, 0, stream>>>(h, aggbf, pU1, v1, pU2, v2, hn,
                                                          pW1n, b1n, gbf, N);
        } else {
            upd_kernel<0><<<gemmBlocks, 256, 0, stream>>>(h, aggbf, pU1, v1, pU2, v2, hn,
                                                          nullptr, nullptr, nullptr, N);
        }
        unsigned short* tmp = h; h = hn; hn = tmp;
    }

    headf_kernel<<<gemmBlocks, 256, 0, stream>>>(h, pOW1, ob1, oW2, ob2, out, N);
}

// Round 17
// 288.882 us; speedup vs baseline: 1.0294x; 1.0294x over previous
//
#include <hip/hip_runtime.h>
#include <hip/hip_bf16.h>
#include <math.h>

typedef short bf16x8 __attribute__((ext_vector_type(8)));
typedef float f32x4 __attribute__((ext_vector_type(4)));
typedef float f32x2 __attribute__((ext_vector_type(2)));
typedef _Float16 f16x2 __attribute__((ext_vector_type(2)));
typedef _Float16 f16x8 __attribute__((ext_vector_type(8)));
typedef __fp16 fp16v2 __attribute__((ext_vector_type(2)));

union ABFrag { int i[4]; bf16x8 v; };
union HFrag { int i[4]; f16x8 v; };

__device__ __forceinline__ float readlane_f(float v, int l) {
    return __uint_as_float(__builtin_amdgcn_readlane(__float_as_uint(v), l));
}

// cold-path pack two f32 -> two bf16 (RNE) in one u32 (lo = a, hi = b)
__device__ __forceinline__ int pack2bf(float a, float b) {
    unsigned ua = __float_as_uint(a);
    unsigned ub = __float_as_uint(b);
    ua = (ua + 0x7FFFu + ((ua >> 16) & 1u)) >> 16;
    ub = (ub + 0x7FFFu + ((ub >> 16) & 1u)) & 0xFFFF0000u;
    return (int)(ua | ub);
}
// hot-path bf16 pack: compiler emits v_cvt_pk_bf16_f32
__device__ __forceinline__ int cvtpk(float a, float b) {
    __hip_bfloat162 h = __float22bfloat162_rn(make_float2(a, b));
    int r; __builtin_memcpy(&r, &h, 4); return r;
}
// fp16 pack: v_cvt_pkrtz_f16_f32
__device__ __forceinline__ int cvtpkh(float a, float b) {
    fp16v2 h = __builtin_amdgcn_cvt_pkrtz(a, b);
    int r; __builtin_memcpy(&r, &h, 4); return r;
}
__device__ __forceinline__ f16x2 cvtpkh2(float a, float b) {
    fp16v2 h = __builtin_amdgcn_cvt_pkrtz(a, b);
    f16x2 r; __builtin_memcpy(&r, &h, 4); return r;
}
__device__ __forceinline__ float bflo(int d) { return __uint_as_float((unsigned)d << 16); }
__device__ __forceinline__ float bfhi(int d) { return __uint_as_float((unsigned)d & 0xFFFF0000u); }

// packed fp16 h-prep: relu(g + a + f*b) on 2 channels, 3 pk ops, no unpack
__device__ __forceinline__ int hp16(int gpk, int apk, int bpk, f16x2 fpk) {
    f16x2 g, a, b;
    __builtin_memcpy(&g, &gpk, 4);
    __builtin_memcpy(&a, &apk, 4);
    __builtin_memcpy(&b, &bpk, 4);
    f16x2 h = g + a + fpk * b;
    f16x2 z = {(_Float16)0.0f, (_Float16)0.0f};
    h = __builtin_elementwise_max(h, z);
    int r; __builtin_memcpy(&r, &h, 4);
    return r;
}

// load pre-packed B-fragment sets
__device__ __forceinline__ void ld8(const int4* __restrict__ P, int lane, ABFrag (&bw)[4][2]) {
#pragma unroll
    for (int nt = 0; nt < 4; ++nt)
#pragma unroll
        for (int kt = 0; kt < 2; ++kt)
            *(int4*)bw[nt][kt].i = P[(nt * 2 + kt) * 64 + lane];
}
__device__ __forceinline__ void ld8h(const int4* __restrict__ P, int lane, HFrag (&bw)[4][2]) {
#pragma unroll
    for (int nt = 0; nt < 4; ++nt)
#pragma unroll
        for (int kt = 0; kt < 2; ++kt)
            *(int4*)bw[nt][kt].i = P[(nt * 2 + kt) * 64 + lane];
}
__device__ __forceinline__ void ld16(const int4* __restrict__ P, int lane, ABFrag (&bw)[4][4]) {
#pragma unroll
    for (int nt = 0; nt < 4; ++nt)
#pragma unroll
        for (int kt = 0; kt < 4; ++kt)
            *(int4*)bw[nt][kt].i = P[(nt * 4 + kt) * 64 + lane];
}

__global__ void zero_int_kernel(int* __restrict__ p, int n) {
    int i = blockIdx.x * blockDim.x + threadIdx.x;
    int stride = gridDim.x * blockDim.x;
    for (; i < n; i += stride) p[i] = 0;
}

// pack all gemm weights into MFMA B-fragment layout (int4 per lane per frag)
// layout (frag-set offsets in int4*64 units):
//   encW2:0  W1a[l]:8+8l  W2[l]:32+8l (fp16!)  U1[l]:56+16l  U2[l]:104+8l  oW1:128
__global__ __launch_bounds__(256)
void wpack_kernel(const float* __restrict__ encW2, const float* __restrict__ mW1,
                  const float* __restrict__ mW2, const float* __restrict__ uW1,
                  const float* __restrict__ uW2, const float* __restrict__ oW1,
                  int4* __restrict__ out) {
    int b = blockIdx.x;
    const float* src; int4* dst; int KT; int F16 = 0;
    if (b == 0)      { src = encW2;                          dst = out;                   KT = 2; }
    else if (b <= 3) { int l = b - 1;  src = mW1 + (size_t)l * 128 * 64; dst = out + (8 + 8 * l) * 64;   KT = 2; }
    else if (b <= 6) { int l = b - 4;  src = mW2 + (size_t)l * 64 * 64;  dst = out + (32 + 8 * l) * 64;  KT = 2; F16 = 1; }
    else if (b <= 9) { int l = b - 7;  src = uW1 + (size_t)l * 128 * 64; dst = out + (56 + 16 * l) * 64; KT = 4; }
    else if (b <= 12){ int l = b - 10; src = uW2 + (size_t)l * 64 * 64;  dst = out + (104 + 8 * l) * 64; KT = 2; }
    else             { src = oW1;                            dst = out + 128 * 64;        KT = 2; }
    int tid = threadIdx.x, lane = tid & 63, w = tid >> 6;
    int n15 = lane & 15, kg = lane >> 4;
    for (int fi = w; fi < 4 * KT; fi += 4) {
        int nt = fi / KT, kt = fi % KT;
        int v[4];
#pragma unroll
        for (int jj = 0; jj < 4; ++jj) {
            int k0 = kt * 32 + kg * 8 + 2 * jj;
            float w0 = src[(size_t)k0 * 64 + nt * 16 + n15];
            float w1 = src[(size_t)(k0 + 1) * 64 + nt * 16 + n15];
            v[jj] = F16 ? cvtpkh(w0, w1) : pack2bf(w0, w1);
        }
        int4 r; r.x = v[0]; r.y = v[1]; r.z = v[2]; r.w = v[3];
        dst[fi * 64 + lane] = r;
    }
}

// XCD-localized histogram: class (blockIdx&7) handles dst range only
__global__ __launch_bounds__(256)
void hist_kernel(const int* __restrict__ EI, int* __restrict__ cnt, int E, int N) {
    int x = blockIdx.x & 7;
    int sl = blockIdx.x >> 3;
    int nsl = gridDim.x >> 3;
    int R = (N + 7) >> 3;
    int lo = x * R;
    int hi = lo + R; if (hi > N) hi = N;
    for (int e = sl * 256 + threadIdx.x; e < E; e += nsl * 256) {
        int dst = EI[E + e];
        if (dst >= lo && dst < hi) atomicAdd(&cnt[dst], 1);
    }
}

// ---- multi-block exclusive scan: cnt[N] -> rowstart[N+1], cursor[N] ----
#define SCAN_B 256

__global__ __launch_bounds__(256)
void scan_part_kernel(const int* __restrict__ cnt, int* __restrict__ bsum, int N) {
    int per = (N + gridDim.x - 1) / gridDim.x;
    int lo = blockIdx.x * per;
    int hi = lo + per; if (hi > N) hi = N;
    int s = 0;
    for (int i = lo + threadIdx.x; i < hi; i += 256) s += cnt[i];
#pragma unroll
    for (int off = 32; off >= 1; off >>= 1) s += __shfl_xor(s, off);
    __shared__ int ws[4];
    if ((threadIdx.x & 63) == 0) ws[threadIdx.x >> 6] = s;
    __syncthreads();
    if (threadIdx.x == 0) bsum[blockIdx.x] = ws[0] + ws[1] + ws[2] + ws[3];
}

__global__ __launch_bounds__(SCAN_B)
void scan_mid_kernel(int* __restrict__ bsum) {
    __shared__ int sbuf[SCAN_B];
    int tid = threadIdx.x;
    int v = bsum[tid];
    sbuf[tid] = v;
    __syncthreads();
#pragma unroll
    for (int d = 1; d < SCAN_B; d <<= 1) {
        int t = (tid >= d) ? sbuf[tid - d] : 0;
        __syncthreads();
        sbuf[tid] += t;
        __syncthreads();
    }
    bsum[tid] = sbuf[tid] - v;   // exclusive
}

__global__ __launch_bounds__(256)
void scan_final_kernel(const int* __restrict__ cnt, const int* __restrict__ bsum,
                       int* __restrict__ rowstart, int* __restrict__ cursor, int N) {
    __shared__ int sbuf[256];
    __shared__ int sbase;
    int per = (N + gridDim.x - 1) / gridDim.x;
    int lo = blockIdx.x * per;
    int hi = lo + per; if (hi > N) hi = N;
    if (threadIdx.x == 0) sbase = bsum[blockIdx.x];
    __syncthreads();
    for (int base = lo; base < hi; base += 256) {
        int i = base + threadIdx.x;
        int v = (i < hi) ? cnt[i] : 0;
        sbuf[threadIdx.x] = v;
        __syncthreads();
#pragma unroll
        for (int d = 1; d < 256; d <<= 1) {
            int t = (threadIdx.x >= d) ? sbuf[threadIdx.x - d] : 0;
            __syncthreads();
            sbuf[threadIdx.x] += t;
            __syncthreads();
        }
        if (i < hi) {
            int ex = sbase + sbuf[threadIdx.x] - v;
            rowstart[i] = ex;
            cursor[i] = ex;
        }
        __syncthreads();
        if (threadIdx.x == 0) sbase += sbuf[255];
        __syncthreads();
    }
    if (blockIdx.x == gridDim.x - 1 && threadIdx.x == 0) rowstart[N] = sbase;
}

// XCD-localized scatter: class (blockIdx&7) writes only its dst range
__global__ __launch_bounds__(256)
void fill_kernel(const int* __restrict__ EI, const float* __restrict__ EF,
                 const float* __restrict__ bp, int* __restrict__ cursor,
                 int2* __restrict__ epack, int E, int N) {
    __shared__ float sbp[64];
    if (threadIdx.x < 64) sbp[threadIdx.x] = bp[threadIdx.x];
    __syncthreads();
    int x = blockIdx.x & 7;
    int sl = blockIdx.x >> 3;
    int nsl = gridDim.x >> 3;
    int R = (N + 7) >> 3;
    int lo = x * R;
    int hi = lo + R; if (hi > N) hi = N;
    for (int e = sl * 256 + threadIdx.x; e < E; e += nsl * 256) {
        int dst = EI[E + e];
        if (dst >= lo && dst < hi) {
            int slot = atomicAdd(&cursor[dst], 1);
            float f = EF[e];
            int sg = 0;
#pragma unroll
            for (int st = 32; st >= 1; st >>= 1)
                if (sg + st <= 64 && sbp[sg + st - 1] < f) sg += st;
            epack[slot] = make_int2(EI[e] | (sg << 25), __float_as_int(f));
        }
    }
}

// sorted breakpoints of f -> relu(f*eW+eB): t_k = -eB_k/eW_k (eW_k != 0)
__global__ __launch_bounds__(64)
void bp_kernel(const float* __restrict__ eW, const float* __restrict__ eB,
               float* __restrict__ bp) {
    int lane = threadIdx.x;
    float w = eW[lane], b = eB[lane];
    float t = (w != 0.f) ? (-b / w) : 1e30f;
    __shared__ float sbp[64];
    int rank = 0;
    for (int j = 0; j < 64; ++j) {
        float tj = readlane_f(t, j);
        rank += (tj < t) || (tj == t && j < lane);
    }
    sbp[rank] = t;
    __syncthreads();
    bp[lane] = sbp[lane];
}

// per (layer, segment): A[j],B[j] summed over active units; stored as packed
// fp16 PAIRS in two planes (A at dwords 0..31, B at 32..63 per segment),
// chunk-XOR-swizzled so msg staging is a raw copy.
__global__ __launch_bounds__(64)
void tab_kernel(const float* __restrict__ eW, const float* __restrict__ eB,
                const float* __restrict__ mW1, const float* __restrict__ bp,
                int* __restrict__ Tpk) {
    int s = blockIdx.x % 65;
    int l = blockIdx.x / 65;
    int j = threadIdx.x;
    float lo = (s == 0) ? 0.f : bp[s - 1];
    float hi = (s == 64) ? 0.f : bp[s];
    float rep;
    if (s == 0) rep = hi - fmaxf(1.f, fabsf(hi));
    else if (s == 64) rep = lo + fmaxf(1.f, fabsf(lo));
    else rep = 0.5f * (lo + hi);
    const float* W1b = mW1 + (size_t)l * 128 * 64 + 64 * 64;
    float A = 0.f, B = 0.f;
    for (int k = 0; k < 64; ++k) {
        float w = eW[k], b = eB[k];
        if (fmaf(rep, w, b) > 0.f) {
            float wv = W1b[k * 64 + j];
            A = fmaf(b, wv, A);
            B = fmaf(w, wv, B);
        }
    }
    float Ao = __shfl_xor(A, 1), Bo = __shfl_xor(B, 1);
    if ((j & 1) == 0) {
        int p = j >> 1;            // pair index 0..31
        int c = p >> 2;            // chunk 0..7
        int base = (s << 6) + (((c ^ (s & 7)) << 2) | (p & 3));
        int* dst = Tpk + (size_t)l * 65 * 64;
        dst[base] = cvtpkh(A, Ao);
        dst[base + 32] = cvtpkh(B, Bo);
    }
}

// first encoder layer, bf16 out: Y[n,j] = relu(b[j] + sum_{k<5} NF[n,k]*W[k,j])
__global__ __launch_bounds__(256)
void enc1_kernel(const float* __restrict__ NF, const float* __restrict__ W,
                 const float* __restrict__ b, unsigned short* __restrict__ Y, int N) {
    int lane = threadIdx.x & 63;
    float w0 = W[0 * 64 + lane], w1 = W[1 * 64 + lane], w2 = W[2 * 64 + lane];
    float w3 = W[3 * 64 + lane], w4 = W[4 * 64 + lane];
    float bv = b[lane];
    int wid = (blockIdx.x * blockDim.x + threadIdx.x) >> 6;
    int nw = (gridDim.x * blockDim.x) >> 6;
    for (int n = wid; n < N; n += nw) {
        float x = (lane < 5) ? NF[n * 5 + lane] : 0.f;
        float acc = bv;
        acc = fmaf(readlane_f(x, 0), w0, acc);
        acc = fmaf(readlane_f(x, 1), w1, acc);
        acc = fmaf(readlane_f(x, 2), w2, acc);
        acc = fmaf(readlane_f(x, 3), w3, acc);
        acc = fmaf(readlane_f(x, 4), w4, acc);
        acc = fmaxf(acc, 0.f);
        float o = __shfl_xor(acc, 1);
        if ((lane & 1) == 0) *(int*)(Y + (size_t)n * 64 + lane) = cvtpk(acc, o);
    }
}

// MFMA node-gemm (bf16 in/out) with optional fused second gemm (Gout fp16 = Y@Wg + bg)
template <int RELU, int FUSE>
__global__ __launch_bounds__(256, 2)
void ngemm_kernel(const unsigned short* __restrict__ X, const int4* __restrict__ pW,
                  const float* __restrict__ b, unsigned short* __restrict__ Y,
                  const int4* __restrict__ pWg, const float* __restrict__ bg,
                  unsigned short* __restrict__ Gout, int N) {
    __shared__ unsigned short sT[4][16 * 72];
    int tid = threadIdx.x;
    int lane = tid & 63, w = tid >> 6;
    int n15 = lane & 15, kg = lane >> 4;
    unsigned short* T = sT[w];
    ABFrag bw[4][2], bwg[4][2];
    ld8(pW, lane, bw);
    if (FUSE) ld8(pWg, lane, bwg);
    float bv[4], bgv[4];
#pragma unroll
    for (int nt = 0; nt < 4; ++nt) {
        bv[nt] = b[nt * 16 + n15];
        bgv[nt] = FUSE ? bg[nt * 16 + n15] : 0.f;
    }

    int wid = (blockIdx.x * blockDim.x + tid) >> 6;
    int nw = (gridDim.x * blockDim.x) >> 6;
    int nTiles = (N + 15) >> 4;
    bool ev = ((n15 & 1) == 0);
    for (int t = wid; t < nTiles; t += nw) {
        int n0 = t << 4;
        int row = n0 + n15; if (row > N - 1) row = N - 1;
        ABFrag A0, A1;
        const unsigned short* xp = X + (size_t)row * 64 + kg * 8;
        *(int4*)A0.i = *(const int4*)xp;
        *(int4*)A1.i = *(const int4*)(xp + 32);
        f32x4 acc[4];
#pragma unroll
        for (int nt = 0; nt < 4; ++nt) {
            acc[nt][0] = bv[nt]; acc[nt][1] = bv[nt];
            acc[nt][2] = bv[nt]; acc[nt][3] = bv[nt];
        }
#pragma unroll
        for (int nt = 0; nt < 4; ++nt) {
            acc[nt] = __builtin_amdgcn_mfma_f32_16x16x32_bf16(A0.v, bw[nt][0].v, acc[nt], 0, 0, 0);
            acc[nt] = __builtin_amdgcn_mfma_f32_16x16x32_bf16(A1.v, bw[nt][1].v, acc[nt], 0, 0, 0);
        }
        if (FUSE) {
            asm volatile("s_waitcnt lgkmcnt(0)" ::: "memory");
            __builtin_amdgcn_sched_barrier(0);
        }
#pragma unroll
        for (int nt = 0; nt < 4; ++nt) {
            float v0 = acc[nt][0], v1 = acc[nt][1], v2 = acc[nt][2], v3 = acc[nt][3];
            if (RELU) {
                v0 = fmaxf(v0, 0.f); v1 = fmaxf(v1, 0.f);
                v2 = fmaxf(v2, 0.f); v3 = fmaxf(v3, 0.f);
            }
            float o0 = __shfl_xor(v0, 1), o1 = __shfl_xor(v1, 1);
            float o2 = __shfl_xor(v2, 1), o3 = __shfl_xor(v3, 1);
            int colb = nt * 16 + (n15 & ~1);
            int p0 = cvtpk(v0, o0), p1 = cvtpk(v1, o1);
            int p2 = cvtpk(o2, v2), p3 = cvtpk(o3, v3);
            if (ev) {
                int r0 = n0 + kg * 4 + 0, r1 = n0 + kg * 4 + 1;
                if (r0 < N) *(int*)(Y + (size_t)r0 * 64 + colb) = p0;
                if (r1 < N) *(int*)(Y + (size_t)r1 * 64 + colb) = p1;
                if (FUSE) {
                    *(int*)(T + (kg * 4 + 0) * 72 + colb) = p0;
                    *(int*)(T + (kg * 4 + 1) * 72 + colb) = p1;
                }
            } else {
                int r2 = n0 + kg * 4 + 2, r3 = n0 + kg * 4 + 3;
                if (r2 < N) *(int*)(Y + (size_t)r2 * 64 + colb) = p2;
                if (r3 < N) *(int*)(Y + (size_t)r3 * 64 + colb) = p3;
                if (FUSE) {
                    *(int*)(T + (kg * 4 + 2) * 72 + colb) = p2;
                    *(int*)(T + (kg * 4 + 3) * 72 + colb) = p3;
                }
            }
        }
        if (FUSE) {
            asm volatile("s_waitcnt lgkmcnt(0)" ::: "memory");
            __builtin_amdgcn_sched_barrier(0);
            ABFrag T0, T1;
            *(int4*)T0.i = *(const int4*)(T + n15 * 72 + kg * 8);
            *(int4*)T1.i = *(const int4*)(T + n15 * 72 + 32 + kg * 8);
            f32x4 g[4];
#pragma unroll
            for (int nt = 0; nt < 4; ++nt) {
                g[nt][0] = bgv[nt]; g[nt][1] = bgv[nt];
                g[nt][2] = bgv[nt]; g[nt][3] = bgv[nt];
            }
#pragma unroll
            for (int nt = 0; nt < 4; ++nt) {
                g[nt] = __builtin_amdgcn_mfma_f32_16x16x32_bf16(T0.v, bwg[nt][0].v, g[nt], 0, 0, 0);
                g[nt] = __builtin_amdgcn_mfma_f32_16x16x32_bf16(T1.v, bwg[nt][1].v, g[nt], 0, 0, 0);
            }
#pragma unroll
            for (int nt = 0; nt < 4; ++nt) {
                float v0 = g[nt][0], v1 = g[nt][1], v2 = g[nt][2], v3 = g[nt][3];
                float o0 = __shfl_xor(v0, 1), o1 = __shfl_xor(v1, 1);
                float o2 = __shfl_xor(v2, 1), o3 = __shfl_xor(v3, 1);
                int colb = nt * 16 + (n15 & ~1);
                if (ev) {
                    int r0 = n0 + kg * 4 + 0, r1 = n0 + kg * 4 + 1;
                    if (r0 < N) *(int*)(Gout + (size_t)r0 * 64 + colb) = cvtpkh(v0, o0);
                    if (r1 < N) *(int*)(Gout + (size_t)r1 * 64 + colb) = cvtpkh(v1, o1);
                } else {
                    int r2 = n0 + kg * 4 + 2, r3 = n0 + kg * 4 + 3;
                    if (r2 < N) *(int*)(Gout + (size_t)r2 * 64 + colb) = cvtpkh(o2, v2);
                    if (r3 < N) *(int*)(Gout + (size_t)r3 * 64 + colb) = cvtpkh(o3, v3);
                }
            }
        }
    }
}

// fused update MLP (+optional next-layer gbf fp16): bf16 activations, packed weights
template <int FUSE>
__global__ __launch_bounds__(256, 2)
void upd_kernel(const unsigned short* __restrict__ X1, const unsigned short* __restrict__ X2,
                const int4* __restrict__ pU1, const float* __restrict__ v1,
                const int4* __restrict__ pU2, const float* __restrict__ v2,
                unsigned short* __restrict__ Y,
                const int4* __restrict__ pWg, const float* __restrict__ bg,
                unsigned short* __restrict__ Gout, int N) {
    __shared__ unsigned short sT[4][16 * 72];
    int tid = threadIdx.x, lane = tid & 63, w = tid >> 6;
    int n15 = lane & 15, kg = lane >> 4;
    unsigned short* T = sT[w];

    ABFrag bw1[4][4], bw2[4][2], bwg[4][2];
    ld16(pU1, lane, bw1);
    ld8(pU2, lane, bw2);
    if (FUSE) ld8(pWg, lane, bwg);
    float b1v[4], b2v[4], bgv[4];
#pragma unroll
    for (int nt = 0; nt < 4; ++nt) {
        b1v[nt] = v1[nt * 16 + n15];
        b2v[nt] = v2[nt * 16 + n15];
        bgv[nt] = FUSE ? bg[nt * 16 + n15] : 0.f;
    }

    int wid = (blockIdx.x * blockDim.x + tid) >> 6;
    int nw = (gridDim.x * blockDim.x) >> 6;
    int nTiles = (N + 15) >> 4;
    bool ev = ((n15 & 1) == 0);
    for (int t = wid; t < nTiles; t += nw) {
        int n0 = t << 4;
        int row = n0 + n15; if (row > N - 1) row = N - 1;
        ABFrag A0, A1, A2, A3;
        const unsigned short* xp = X1 + (size_t)row * 64 + kg * 8;
        *(int4*)A0.i = *(const int4*)xp;
        *(int4*)A1.i = *(const int4*)(xp + 32);
        const unsigned short* yp = X2 + (size_t)row * 64 + kg * 8;
        *(int4*)A2.i = *(const int4*)yp;
        *(int4*)A3.i = *(const int4*)(yp + 32);
        f32x4 a1[4];
#pragma unroll
        for (int nt = 0; nt < 4; ++nt) {
            a1[nt][0] = b1v[nt]; a1[nt][1] = b1v[nt];
            a1[nt][2] = b1v[nt]; a1[nt][3] = b1v[nt];
        }
#pragma unroll
        for (int nt = 0; nt < 4; ++nt) {
            a1[nt] = __builtin_amdgcn_mfma_f32_16x16x32_bf16(A0.v, bw1[nt][0].v, a1[nt], 0, 0, 0);
            a1[nt] = __builtin_amdgcn_mfma_f32_16x16x32_bf16(A1.v, bw1[nt][1].v, a1[nt], 0, 0, 0);
            a1[nt] = __builtin_amdgcn_mfma_f32_16x16x32_bf16(A2.v, bw1[nt][2].v, a1[nt], 0, 0, 0);
            a1[nt] = __builtin_amdgcn_mfma_f32_16x16x32_bf16(A3.v, bw1[nt][3].v, a1[nt], 0, 0, 0);
        }
        // t1 (relu, bf16) -> per-wave LDS tile, stride 72
        asm volatile("s_waitcnt lgkmcnt(0)" ::: "memory");
        __builtin_amdgcn_sched_barrier(0);
#pragma unroll
        for (int nt = 0; nt < 4; ++nt) {
            float v0 = fmaxf(a1[nt][0], 0.f), v1_ = fmaxf(a1[nt][1], 0.f);
            float v2_ = fmaxf(a1[nt][2], 0.f), v3 = fmaxf(a1[nt][3], 0.f);
            float o0 = __shfl_xor(v0, 1), o1 = __shfl_xor(v1_, 1);
            float o2 = __shfl_xor(v2_, 1), o3 = __shfl_xor(v3, 1);
            int colb = nt * 16 + (n15 & ~1);
            if (ev) {
                *(int*)(T + (kg * 4 + 0) * 72 + colb) = cvtpk(v0, o0);
                *(int*)(T + (kg * 4 + 1) * 72 + colb) = cvtpk(v1_, o1);
            } else {
                *(int*)(T + (kg * 4 + 2) * 72 + colb) = cvtpk(o2, v2_);
                *(int*)(T + (kg * 4 + 3) * 72 + colb) = cvtpk(o3, v3);
            }
        }
        asm volatile("s_waitcnt lgkmcnt(0)" ::: "memory");
        __builtin_amdgcn_sched_barrier(0);
        ABFrag T0, T1;
        *(int4*)T0.i = *(const int4*)(T + n15 * 72 + kg * 8);
        *(int4*)T1.i = *(const int4*)(T + n15 * 72 + 32 + kg * 8);
        f32x4 a2[4];
#pragma unroll
        for (int nt = 0; nt < 4; ++nt) {
            a2[nt][0] = b2v[nt]; a2[nt][1] = b2v[nt];
            a2[nt][2] = b2v[nt]; a2[nt][3] = b2v[nt];
        }
#pragma unroll
        for (int nt = 0; nt < 4; ++nt) {
            a2[nt] = __builtin_amdgcn_mfma_f32_16x16x32_bf16(T0.v, bw2[nt][0].v, a2[nt], 0, 0, 0);
            a2[nt] = __builtin_amdgcn_mfma_f32_16x16x32_bf16(T1.v, bw2[nt][1].v, a2[nt], 0, 0, 0);
        }
        asm volatile("s_waitcnt lgkmcnt(0)" ::: "memory");
        __builtin_amdgcn_sched_barrier(0);
#pragma unroll
        for (int nt = 0; nt < 4; ++nt) {
            float v0 = fmaxf(a2[nt][0], 0.f), v1_ = fmaxf(a2[nt][1], 0.f);
            float v2_ = fmaxf(a2[nt][2], 0.f), v3 = fmaxf(a2[nt][3], 0.f);
            float o0 = __shfl_xor(v0, 1), o1 = __shfl_xor(v1_, 1);
            float o2 = __shfl_xor(v2_, 1), o3 = __shfl_xor(v3, 1);
            int colb = nt * 16 + (n15 & ~1);
            int p0 = cvtpk(v0, o0), p1 = cvtpk(v1_, o1);
            int p2 = cvtpk(o2, v2_), p3 = cvtpk(o3, v3);
            if (ev) {
                int r0 = n0 + kg * 4 + 0, r1 = n0 + kg * 4 + 1;
                if (r0 < N) *(int*)(Y + (size_t)r0 * 64 + colb) = p0;
                if (r1 < N) *(int*)(Y + (size_t)r1 * 64 + colb) = p1;
                if (FUSE) {
                    *(int*)(T + (kg * 4 + 0) * 72 + colb) = p0;
                    *(int*)(T + (kg * 4 + 1) * 72 + colb) = p1;
                }
            } else {
                int r2 = n0 + kg * 4 + 2, r3 = n0 + kg * 4 + 3;
                if (r2 < N) *(int*)(Y + (size_t)r2 * 64 + colb) = p2;
                if (r3 < N) *(int*)(Y + (size_t)r3 * 64 + colb) = p3;
                if (FUSE) {
                    *(int*)(T + (kg * 4 + 2) * 72 + colb) = p2;
                    *(int*)(T + (kg * 4 + 3) * 72 + colb) = p3;
                }
            }
        }
        if (FUSE) {
            asm volatile("s_waitcnt lgkmcnt(0)" ::: "memory");
            __builtin_amdgcn_sched_barrier(0);
            ABFrag G0, G1;
            *(int4*)G0.i = *(const int4*)(T + n15 * 72 + kg * 8);
            *(int4*)G1.i = *(const int4*)(T + n15 * 72 + 32 + kg * 8);
            f32x4 g[4];
#pragma unroll
            for (int nt = 0; nt < 4; ++nt) {
                g[nt][0] = bgv[nt]; g[nt][1] = bgv[nt];
                g[nt][2] = bgv[nt]; g[nt][3] = bgv[nt];
            }
#pragma unroll
            for (int nt = 0; nt < 4; ++nt) {
                g[nt] = __builtin_amdgcn_mfma_f32_16x16x32_bf16(G0.v, bwg[nt][0].v, g[nt], 0, 0, 0);
                g[nt] = __builtin_amdgcn_mfma_f32_16x16x32_bf16(G1.v, bwg[nt][1].v, g[nt], 0, 0, 0);
            }
#pragma unroll
            for (int nt = 0; nt < 4; ++nt) {
                float v0 = g[nt][0], v1_ = g[nt][1], v2_ = g[nt][2], v3 = g[nt][3];
                float o0 = __shfl_xor(v0, 1), o1 = __shfl_xor(v1_, 1);
                float o2 = __shfl_xor(v2_, 1), o3 = __shfl_xor(v3, 1);
                int colb = nt * 16 + (n15 & ~1);
                if (ev) {
                    int r0 = n0 + kg * 4 + 0, r1 = n0 + kg * 4 + 1;
                    if (r0 < N) *(int*)(Gout + (size_t)r0 * 64 + colb) = cvtpkh(v0, o0);
                    if (r1 < N) *(int*)(Gout + (size_t)r1 * 64 + colb) = cvtpkh(v1_, o1);
                } else {
                    int r2 = n0 + kg * 4 + 2, r3 = n0 + kg * 4 + 3;
                    if (r2 < N) *(int*)(Gout + (size_t)r2 * 64 + colb) = cvtpkh(o2, v2_);
                    if (r3 < N) *(int*)(Gout + (size_t)r3 * 64 + colb) = cvtpkh(o3, v3);
                }
            }
        }
    }
}

// node-per-wave fp16 MFMA message kernel (no atomics), XCD-local strided nodes,
// packed fp16 table (A/B planes) + packed fp16 h-prep; bf16 Agg out.
__global__ __launch_bounds__(256, 4)
void msg_mfma_kernel(const unsigned short* __restrict__ Gh, const int* __restrict__ rowstart,
                     const int2* __restrict__ epack, const int* __restrict__ Tpk,
                     const int4* __restrict__ pW2, const float* __restrict__ b2p,
                     unsigned short* __restrict__ AggBf, int N) {
    __shared__ int sT[65 * 64];
    int tid = threadIdx.x;
    for (int i = tid; i < 65 * 64; i += 256) sT[i] = Tpk[i];
    int lane = tid & 63;
    int n15 = lane & 15;
    int kg = lane >> 4;

    HFrag bw[4][2];
    ld8h(pW2, lane, bw);
    float b2v[4], pb2[4];
#pragma unroll
    for (int nt = 0; nt < 4; ++nt) { b2v[nt] = b2p[nt * 16 + n15]; pb2[nt] = fmaxf(b2v[nt], 0.f); }
    __syncthreads();

    // XCD-local node range (matches fill's dst partition), strided across waves
    int x = blockIdx.x & 7;
    int R = (N + 7) >> 3;
    int lo = x * R;
    int hi = lo + R; if (hi > N) hi = N;
    int wic = ((blockIdx.x >> 3) << 2) + (tid >> 6);
    int nwc = (gridDim.x >> 3) << 2;

    const f32x4 z4 = {0.f, 0.f, 0.f, 0.f};
    for (int n = lo + wic; n < hi; n += nwc) {
        int beg = rowstart[n], end = rowstart[n + 1];
        int d = end - beg;
        float na[4] = {0.f, 0.f, 0.f, 0.f};
        int e0 = beg + n15;
        int2 epNext = epack[(e0 < end) ? e0 : beg];
        for (int t0 = beg; t0 < end; t0 += 16) {
            int2 ep = epNext;
            int t1 = t0 + 16;
            if (t1 < end) {
                int e1 = t1 + n15;
                epNext = epack[(e1 < end) ? e1 : beg];
            }
            int src = ep.x & 0x1FFFFFF;
            int sg = (int)(((unsigned)ep.x) >> 25);
            f16x2 fpk = cvtpkh2(__int_as_float(ep.y), __int_as_float(ep.y));
            const unsigned short* gp = Gh + (size_t)src * 64 + kg * 8;
            int4 ga = *(const int4*)gp;
            int4 gb = *(const int4*)(gp + 32);
            int sgb = sg << 6, sx = sg & 7;
            int4 tA0 = *(const int4*)&sT[sgb + (((kg ^ sx)) << 2)];
            int4 tA1 = *(const int4*)&sT[sgb + ((((4 + kg) ^ sx)) << 2)];
            int4 tB0 = *(const int4*)&sT[sgb + 32 + (((kg ^ sx)) << 2)];
            int4 tB1 = *(const int4*)&sT[sgb + 32 + ((((4 + kg) ^ sx)) << 2)];
            HFrag A0, A1;
            A0.i[0] = hp16(ga.x, tA0.x, tB0.x, fpk);
            A0.i[1] = hp16(ga.y, tA0.y, tB0.y, fpk);
            A0.i[2] = hp16(ga.z, tA0.z, tB0.z, fpk);
            A0.i[3] = hp16(ga.w, tA0.w, tB0.w, fpk);
            A1.i[0] = hp16(gb.x, tA1.x, tB1.x, fpk);
            A1.i[1] = hp16(gb.y, tA1.y, tB1.y, fpk);
            A1.i[2] = hp16(gb.z, tA1.z, tB1.z, fpk);
            A1.i[3] = hp16(gb.w, tA1.w, tB1.w, fpk);
            int rem = end - t0;
            if (rem < 16) {
                // zero pad rows (lanes); they contribute exactly relu(b2) per col,
                // removed by the per-node correction below
                int zm = (n15 < rem) ? -1 : 0;
#pragma unroll
                for (int j = 0; j < 4; ++j) { A0.i[j] &= zm; A1.i[j] &= zm; }
            }
            f32x4 acc[4];
#pragma unroll
            for (int nt = 0; nt < 4; ++nt) {
                acc[nt][0] = b2v[nt]; acc[nt][1] = b2v[nt];
                acc[nt][2] = b2v[nt]; acc[nt][3] = b2v[nt];
            }
#pragma unroll
            for (int nt = 0; nt < 4; ++nt) {
                acc[nt] = __builtin_amdgcn_mfma_f32_16x16x32_f16(A0.v, bw[nt][0].v, acc[nt], 0, 0, 0);
                acc[nt] = __builtin_amdgcn_mfma_f32_16x16x32_f16(A1.v, bw[nt][1].v, acc[nt], 0, 0, 0);
            }
#pragma unroll
            for (int nt = 0; nt < 4; ++nt) {
                f32x4 m = __builtin_elementwise_max(acc[nt], z4);
                na[nt] += (m[0] + m[1]) + (m[2] + m[3]);
            }
        }
        // cross-lane kg reduction, once per node
#pragma unroll
        for (int nt = 0; nt < 4; ++nt) {
            float v = na[nt];
            v += __shfl_xor(v, 16);
            v += __shfl_xor(v, 32);
            na[nt] = v;
        }
        // remove pad-row contributions, mean, select col = lane, store bf16
        int tiles = (d + 15) >> 4;
        float pad = (float)((tiles << 4) - d);
        float invd = (d > 0) ? (1.f / (float)d) : 1.f;
        float s0 = fmaf(-pad, pb2[0], na[0]);
        float s1 = fmaf(-pad, pb2[1], na[1]);
        float s2 = fmaf(-pad, pb2[2], na[2]);
        float s3 = fmaf(-pad, pb2[3], na[3]);
        float sel = s0;
        sel = (kg == 1) ? s1 : sel;
        sel = (kg == 2) ? s2 : sel;
        sel = (kg == 3) ? s3 : sel;
        sel *= invd;
        float o = __shfl_xor(sel, 1);
        if ((lane & 1) == 0) *(int*)(AggBf + (size_t)n * 64 + lane) = cvtpk(sel, o);
    }
}

// fused head: t = relu(X1@W1+b1); pred = t@W2+b2; out = 2pi*sigmoid(pred); X1 bf16
__global__ __launch_bounds__(256, 2)
void headf_kernel(const unsigned short* __restrict__ X1, const int4* __restrict__ pW1,
                  const float* __restrict__ b1, const float* __restrict__ W2,
                  const float* __restrict__ b2, float* __restrict__ out, int N) {
    int tid = threadIdx.x, lane = tid & 63;
    int n15 = lane & 15, kg = lane >> 4;
    ABFrag bw[4][2];
    ld8(pW1, lane, bw);
    float bv[4];
#pragma unroll
    for (int nt = 0; nt < 4; ++nt) bv[nt] = b1[nt * 16 + n15];
    float w2r[3][4];
#pragma unroll
    for (int nt = 0; nt < 4; ++nt) {
        int col = nt * 16 + n15;
        w2r[0][nt] = W2[col * 3 + 0];
        w2r[1][nt] = W2[col * 3 + 1];
        w2r[2][nt] = W2[col * 3 + 2];
    }
    float b20 = b2[0], b21 = b2[1], b22 = b2[2];
    const float TWO_PI = 6.283185307179586f;

    int wid = (blockIdx.x * blockDim.x + tid) >> 6;
    int nw = (gridDim.x * blockDim.x) >> 6;
    int nTiles = (N + 15) >> 4;
    for (int t = wid; t < nTiles; t += nw) {
        int n0 = t << 4;
        int row = n0 + n15; if (row > N - 1) row = N - 1;
        ABFrag A0, A1;
        const unsigned short* xp = X1 + (size_t)row * 64 + kg * 8;
        *(int4*)A0.i = *(const int4*)xp;
        *(int4*)A1.i = *(const int4*)(xp + 32);
        f32x4 acc[4];
#pragma unroll
        for (int nt = 0; nt < 4; ++nt) {
            acc[nt][0] = bv[nt]; acc[nt][1] = bv[nt];
            acc[nt][2] = bv[nt]; acc[nt][3] = bv[nt];
        }
#pragma unroll
        for (int nt = 0; nt < 4; ++nt) {
            acc[nt] = __builtin_amdgcn_mfma_f32_16x16x32_bf16(A0.v, bw[nt][0].v, acc[nt], 0, 0, 0);
            acc[nt] = __builtin_amdgcn_mfma_f32_16x16x32_bf16(A1.v, bw[nt][1].v, acc[nt], 0, 0, 0);
        }
#pragma unroll
        for (int r = 0; r < 4; ++r) {
            float p0 = 0.f, p1 = 0.f, p2 = 0.f;
#pragma unroll
            for (int nt = 0; nt < 4; ++nt) {
                float tv = fmaxf(acc[nt][r], 0.f);
                p0 = fmaf(tv, w2r[0][nt], p0);
                p1 = fmaf(tv, w2r[1][nt], p1);
                p2 = fmaf(tv, w2r[2][nt], p2);
            }
#pragma unroll
            for (int off = 1; off <= 8; off <<= 1) {
                p0 += __shfl_xor(p0, off);
                p1 += __shfl_xor(p1, off);
                p2 += __shfl_xor(p2, off);
            }
            int rr = n0 + kg * 4 + r;
            if (n15 == 0 && rr < N) {
                float v0 = p0 + b20, v1 = p1 + b21, v2 = p2 + b22;
                out[rr * 3 + 0] = TWO_PI / (1.f + expf(-v0));
                out[rr * 3 + 1] = TWO_PI / (1.f + expf(-v1));
                out[rr * 3 + 2] = TWO_PI / (1.f + expf(-v2));
            }
        }
    }
}

extern "C" void kernel_launch(void* const* d_in, const int* in_sizes, int n_in,
                              void* d_out, int out_size, void* d_ws, size_t ws_size,
                              hipStream_t stream) {
    const float* nf    = (const float*)d_in[0];
    const int*   ei    = (const int*)d_in[1];
    const float* ef    = (const float*)d_in[2];
    const float* encW1 = (const float*)d_in[3];
    const float* encb1 = (const float*)d_in[4];
    const float* encW2 = (const float*)d_in[5];
    const float* encb2 = (const float*)d_in[6];
    const float* eeW   = (const float*)d_in[7];
    const float* eeb   = (const float*)d_in[8];
    const float* mW1   = (const float*)d_in[9];
    const float* mb1   = (const float*)d_in[10];
    const float* mW2   = (const float*)d_in[11];
    const float* mb2   = (const float*)d_in[12];
    const float* uW1   = (const float*)d_in[13];
    const float* ub1   = (const float*)d_in[14];
    const float* uW2   = (const float*)d_in[15];
    const float* ub2   = (const float*)d_in[16];
    const float* oW1   = (const float*)d_in[17];
    const float* ob1   = (const float*)d_in[18];
    const float* oW2   = (const float*)d_in[19];
    const float* ob2   = (const float*)d_in[20];
    float* out = (float*)d_out;

    int N = in_sizes[0] / 5;   // 50000
    int E = in_sizes[2];       // 800000
    size_t N64 = (size_t)N * 64;

    unsigned short* hA    = (unsigned short*)d_ws;       // N64 bf16
    unsigned short* hB    = hA + N64;                    // N64 bf16
    unsigned short* gbf   = hB + N64;                    // N64 fp16 (also enc tmp bf16)
    unsigned short* aggbf = gbf + N64;                   // N64 bf16
    int2* epack = (int2*)(aggbf + N64);                  // E int2
    float* bp   = (float*)(epack + E);                   // 64
    int* Tpk    = (int*)(bp + 64);                       // 3*65*64
    int4* pw    = (int4*)(Tpk + 3 * 65 * 64);            // 136*64 int4 (packed weights)
    int* rowstart = (int*)(pw + 136 * 64);               // N+8
    int* cursor   = rowstart + N + 8;                    // N
    int* dcnt     = cursor + N;                          // N
    int* bsum     = dcnt + N;                            // SCAN_B

    const int4* pEncW2 = pw;
    const int4* pW1a0  = pw + (size_t)8 * 64;
    const int4* pOW1   = pw + (size_t)128 * 64;

    int gemmBlocks = ((N + 15) / 16 + 7) / 8;            // 2 tiles per wave

    // packed weights + piecewise-linear tables (fixed inputs)
    wpack_kernel<<<14, 256, 0, stream>>>(encW2, mW1, mW2, uW1, uW2, oW1, pw);
    bp_kernel<<<1, 64, 0, stream>>>(eeW, eeb, bp);
    tab_kernel<<<195, 64, 0, stream>>>(eeW, eeb, mW1, bp, Tpk);

    // node encoder (+fused fp16 gbf for layer 0)
    enc1_kernel<<<512, 256, 0, stream>>>(nf, encW1, encb1, gbf, N);
    ngemm_kernel<1, 1><<<gemmBlocks, 256, 0, stream>>>(gbf, pEncW2, encb2, hA,
                                                       pW1a0, mb1, gbf, N);

    // CSR build (dst-sorted edge list), XCD-localized hist/scatter
    zero_int_kernel<<<256, 256, 0, stream>>>(dcnt, N);
    hist_kernel<<<2048, 256, 0, stream>>>(ei, dcnt, E, N);
    scan_part_kernel<<<SCAN_B, 256, 0, stream>>>(dcnt, bsum, N);
    scan_mid_kernel<<<1, SCAN_B, 0, stream>>>(bsum);
    scan_final_kernel<<<SCAN_B, 256, 0, stream>>>(dcnt, bsum, rowstart, cursor, N);
    fill_kernel<<<2048, 256, 0, stream>>>(ei, ef, bp, cursor, epack, E, N);

    unsigned short* h  = hA;
    unsigned short* hn = hB;
    for (int l = 0; l < 3; ++l) {
        const int4* pW2 = pw + (size_t)(32 + 8 * l) * 64;
        const float* b2 = mb2 + l * 64;
        // aggbf = mean over in-edges of relu(relu(G+ce)@W2+b2)   (fp16 datapath)
        msg_mfma_kernel<<<2048, 256, 0, stream>>>(gbf, rowstart, epack,
                                                  Tpk + (size_t)l * 65 * 64,
                                                  pW2, b2, aggbf, N);
        const int4* pU1 = pw + (size_t)(56 + 16 * l) * 64;
        const int4* pU2 = pw + (size_t)(104 + 8 * l) * 64;
        const float* v1 = ub1 + l * 64;
        const float* v2 = ub2 + l * 64;
        // hn = relu(relu([h|aggbf]@U1+v1)@U2+v2)  (+fused next-layer fp16 gbf)
        if (l < 2) {
            const int4* pW1n = pw + (size_t)(8 + 8 * (l + 1)) * 64;
            const float* b1n = mb1 + (l + 1) * 64;
            upd_kernel<1><<<gemmBlocks, 256, 0, stream>>>(h, aggbf, pU1, v1, pU2, v2, hn,
                                                          pW1n, b1n, gbf, N);
        } else {
            upd_kernel<0><<<gemmBlocks, 256, 0, stream>>>(h, aggbf, pU1, v1, pU2, v2, hn,
                                                          nullptr, nullptr, nullptr, N);
        }
        unsigned short* tmp = h; h = hn; hn = tmp;
    }

    headf_kernel<<<gemmBlocks, 256, 0, stream>>>(h, pOW1, ob1, oW2, ob2, out, N);
}